// Round 2
// baseline (1412.580 us; speedup 1.0000x reference)
//
#include <hip/hip_runtime.h>
#include <hip/hip_bf16.h>
#include <stdint.h>

typedef __attribute__((ext_vector_type(8))) short bf16x8;
typedef __attribute__((ext_vector_type(4))) float f32x4;
typedef unsigned short ushort_t;
typedef unsigned int uint_t;

__device__ __forceinline__ unsigned short f2bf(float f) {
  unsigned u = __float_as_uint(f);
  u += 0x7fffu + ((u >> 16) & 1u);
  return (unsigned short)(u >> 16);
}
__device__ __forceinline__ float bf2f(unsigned u16) {
  return __uint_as_float(u16 << 16);
}

// ---- dual-dtype helpers for the node-state buffer h ------------------------
template <typename HT> struct H2;
template <> struct H2<float> {
  static __device__ __forceinline__ float2 ld(const float* h, size_t i) {
    return ((const float2*)h)[i];
  }
  static __device__ __forceinline__ void st(float* h, size_t i, float2 v) {
    ((float2*)h)[i] = v;
  }
};
template <> struct H2<ushort_t> {
  static __device__ __forceinline__ float2 ld(const ushort_t* h, size_t i) {
    uint_t u = ((const uint_t*)h)[i];
    float2 r;
    r.x = bf2f(u & 0xffffu);
    r.y = bf2f(u >> 16);
    return r;
  }
  static __device__ __forceinline__ void st(ushort_t* h, size_t i, float2 v) {
    uint_t u = (uint_t)f2bf(v.x) | ((uint_t)f2bf(v.y) << 16);
    ((uint_t*)h)[i] = u;
  }
};

__global__ void k_zero(int* __restrict__ p, int n) {
  int i = blockIdx.x * blockDim.x + threadIdx.x;
  if (i < n) p[i] = 0;
}

// ---- weights -> bf16, swizzled [l][nt(4)][kt(16)][kg(4)][col(128)][j(8)]
// maps to W[l][k = kt*32+kg*8+j][n = nt*128+col]
__global__ void k_prep_w(const float* __restrict__ W, ushort_t* __restrict__ Wt, int total) {
  int idx = blockIdx.x * blockDim.x + threadIdx.x;
  if (idx >= total) return;
  int j   = idx & 7;
  int col = (idx >> 3) & 127;
  int kg  = (idx >> 10) & 3;
  int kt  = (idx >> 12) & 15;
  int nt  = (idx >> 16) & 3;
  int l   = idx >> 18;
  int k = kt * 32 + kg * 8 + j;
  int n = nt * 128 + col;
  Wt[idx] = f2bf(W[((size_t)(l * 512 + k)) * 512 + n]);
}

// ---- h = log1p(x) @ expW + expb
template <typename HT>
__global__ void k_expand(const float* __restrict__ x, const float* __restrict__ eW,
                         const float* __restrict__ eb, HT* __restrict__ h, int N) {
  int n = blockIdx.x;
  int t = threadIdx.x;
  __shared__ float lx[16];
  if (t < 11) lx[t] = log1pf(x[n * 11 + t]);
  __syncthreads();
  const float2* W2 = (const float2*)eW;
  float2 acc = ((const float2*)eb)[t];
#pragma unroll
  for (int f = 0; f < 11; ++f) {
    float2 w = W2[f * 256 + t];
    acc.x += lx[f] * w.x;
    acc.y += lx[f] * w.y;
  }
  H2<HT>::st(h, (size_t)n * 256 + t, acc);
}

__global__ void k_deg(const int* __restrict__ dst, int* __restrict__ deg, int E) {
  int e = blockIdx.x * blockDim.x + threadIdx.x;
  if (e < E) atomicAdd(&deg[dst[e]], 1);
}

__global__ void k_dinv(const int* __restrict__ deg, float* __restrict__ dinv,
                       float* __restrict__ selfn, int N) {
  int n = blockIdx.x * blockDim.x + threadIdx.x;
  if (n >= N) return;
  float d = (float)deg[n] + 2.0f;
  dinv[n] = rsqrtf(d);
  selfn[n] = 2.0f / d;
}

// ---- 2-level exclusive scan of deg -> off (CSR offsets)
__global__ void k_scan_a(const int* __restrict__ deg, int* __restrict__ off,
                         int* __restrict__ bsum, int N) {
  __shared__ int sd[256];
  int t = threadIdx.x;
  int i0 = blockIdx.x * 1024 + t * 4;
  int d[4];
#pragma unroll
  for (int j = 0; j < 4; ++j) d[j] = (i0 + j < N) ? deg[i0 + j] : 0;
  int ts = d[0] + d[1] + d[2] + d[3];
  sd[t] = ts;
  __syncthreads();
  for (int o = 1; o < 256; o <<= 1) {
    int v = (t >= o) ? sd[t - o] : 0;
    __syncthreads();
    sd[t] += v;
    __syncthreads();
  }
  int incl = sd[t];
  int run = incl - ts;
#pragma unroll
  for (int j = 0; j < 4; ++j) {
    if (i0 + j < N) off[i0 + j] = run;
    run += d[j];
  }
  if (t == 255) bsum[blockIdx.x] = incl;
}

__global__ void k_scan_b(const int* __restrict__ bsum, int* __restrict__ bpre, int nb,
                         int* __restrict__ off, int N, int E) {
  __shared__ int sd[256];
  int t = threadIdx.x;
  int v = (t < nb) ? bsum[t] : 0;
  sd[t] = v;
  __syncthreads();
  for (int o = 1; o < 256; o <<= 1) {
    int u = (t >= o) ? sd[t - o] : 0;
    __syncthreads();
    sd[t] += u;
    __syncthreads();
  }
  if (t < nb) bpre[t] = sd[t] - v;
  if (t == 0) off[N] = E;
}

__global__ void k_scan_c(int* __restrict__ off, const int* __restrict__ bpre, int N) {
  int i = blockIdx.x * blockDim.x + threadIdx.x;
  if (i < N) off[i] += bpre[i >> 10];
}

__global__ void k_fill(const int* __restrict__ src, const int* __restrict__ dst,
                       const int* __restrict__ off, int* __restrict__ cur,
                       int* __restrict__ ssrc, int E) {
  int e = blockIdx.x * blockDim.x + threadIdx.x;
  if (e >= E) return;
  int t = dst[e];
  int p = atomicAdd(&cur[t], 1);
  ssrc[off[t] + p] = src[e];
}

// ---- A fragment loader: 16 k-values starting at p -> two bf16x8
template <typename HT>
__device__ __forceinline__ void load_a16(const HT* p, bool valid, bf16x8& v0, bf16x8& v1);

template <>
__device__ __forceinline__ void load_a16<float>(const float* p, bool valid, bf16x8& v0, bf16x8& v1) {
  float4 f0, f1, f2, f3;
  if (valid) {
    const float4* q = (const float4*)p;
    f0 = q[0]; f1 = q[1]; f2 = q[2]; f3 = q[3];
  } else {
    f0 = f1 = f2 = f3 = make_float4(0.f, 0.f, 0.f, 0.f);
  }
  union { bf16x8 v; unsigned short s[8]; } u0, u1;
  u0.s[0] = f2bf(f0.x); u0.s[1] = f2bf(f0.y); u0.s[2] = f2bf(f0.z); u0.s[3] = f2bf(f0.w);
  u0.s[4] = f2bf(f1.x); u0.s[5] = f2bf(f1.y); u0.s[6] = f2bf(f1.z); u0.s[7] = f2bf(f1.w);
  u1.s[0] = f2bf(f2.x); u1.s[1] = f2bf(f2.y); u1.s[2] = f2bf(f2.z); u1.s[3] = f2bf(f2.w);
  u1.s[4] = f2bf(f3.x); u1.s[5] = f2bf(f3.y); u1.s[6] = f2bf(f3.z); u1.s[7] = f2bf(f3.w);
  v0 = u0.v; v1 = u1.v;
}

template <>
__device__ __forceinline__ void load_a16<ushort_t>(const ushort_t* p, bool valid, bf16x8& v0, bf16x8& v1) {
  if (valid) {
    v0 = ((const bf16x8*)p)[0];
    v1 = ((const bf16x8*)p)[1];
  } else {
    v0 = (bf16x8){0, 0, 0, 0, 0, 0, 0, 0};
    v1 = v0;
  }
}

// ---- xw = h @ W[l]  (bf16 MFMA, 128x128 tile, 4 waves of 64x64, BK=32)
template <typename HT>
__global__ __launch_bounds__(256) void k_gemm(const HT* __restrict__ h,
                                              const ushort_t* __restrict__ Wt,
                                              ushort_t* __restrict__ xw, int N) {
  __shared__ alignas(16) short Alds[4 * 128 * 8];  // [kg][row][8]
  __shared__ alignas(16) short Blds[4 * 128 * 8];  // [kg][col][8]
  const int tid = threadIdx.x;
  const int m0 = blockIdx.x * 128;
  const int nt = blockIdx.y;
  const int wv = tid >> 6, ln = tid & 63;
  const int wrow = wv >> 1, wcol = wv & 1;
  const int l15 = ln & 15, l4 = ln >> 4;

  f32x4 acc[4][4];
#pragma unroll
  for (int i = 0; i < 4; ++i)
#pragma unroll
    for (int j = 0; j < 4; ++j) acc[i][j] = (f32x4){0.f, 0.f, 0.f, 0.f};

  const int r = tid >> 1, hh = tid & 1;
  const int grow = m0 + r;
  const bool valid = grow < N;
  const HT* hrow = h + (size_t)grow * 512 + hh * 16;
  const int abase0 = ((hh * 2 + 0) * 128 + r) * 8;
  const int abase1 = ((hh * 2 + 1) * 128 + r) * 8;

  for (int kt = 0; kt < 16; ++kt) {
    __syncthreads();
    // B stage: 8KB linear global_load_lds (Wt pre-swizzled to LDS layout)
    {
      const ushort_t* wt = Wt + (((size_t)nt * 16 + kt) << 12);
      const ushort_t* g1 = wt + ((wv * 64 + ln) << 3);
      const ushort_t* g2 = g1 + 2048;
      __builtin_amdgcn_global_load_lds(
          (const __attribute__((address_space(1))) unsigned int*)g1,
          (__attribute__((address_space(3))) unsigned int*)&Blds[(wv * 64) << 3], 16, 0, 0);
      __builtin_amdgcn_global_load_lds(
          (const __attribute__((address_space(1))) unsigned int*)g2,
          (__attribute__((address_space(3))) unsigned int*)&Blds[(256 + wv * 64) << 3], 16, 0, 0);
    }
    // A stage: load 16 k-values (convert if f32), ds_write
    {
      bf16x8 v0, v1;
      load_a16<HT>(hrow + kt * 32, valid, v0, v1);
      *(bf16x8*)&Alds[abase0] = v0;
      *(bf16x8*)&Alds[abase1] = v1;
    }
    __syncthreads();
    bf16x8 a[4], b[4];
#pragma unroll
    for (int i = 0; i < 4; ++i) {
      a[i] = *(const bf16x8*)&Alds[(l4 * 128 + wrow * 64 + i * 16 + l15) * 8];
      b[i] = *(const bf16x8*)&Blds[(l4 * 128 + wcol * 64 + i * 16 + l15) * 8];
    }
#pragma unroll
    for (int i = 0; i < 4; ++i)
#pragma unroll
      for (int j = 0; j < 4; ++j)
        acc[i][j] = __builtin_amdgcn_mfma_f32_16x16x32_bf16(a[i], b[j], acc[i][j], 0, 0, 0);
  }

#pragma unroll
  for (int i = 0; i < 4; ++i) {
    int row0 = m0 + wrow * 64 + i * 16 + l4 * 4;
#pragma unroll
    for (int v = 0; v < 4; ++v) {
      int row = row0 + v;
      if (row < N) {
#pragma unroll
        for (int j = 0; j < 4; ++j) {
          int col = nt * 128 + wcol * 64 + j * 16 + l15;
          xw[(size_t)row * 512 + col] = f2bf(acc[i][j][v]);
        }
      }
    }
  }
}

// ---- fused: agg = sum_in enorm*xw[src] + self*xw[n] + b ; h += relu(agg)
template <typename HT>
__global__ void k_agg(const ushort_t* __restrict__ xw, HT* __restrict__ h,
                      const int* __restrict__ off, const int* __restrict__ ssrc,
                      const float* __restrict__ dinv, const float* __restrict__ selfn,
                      const float* __restrict__ gb) {
  int n = blockIdx.x;
  int t = threadIdx.x;
  int s0 = off[n], s1 = off[n + 1];
  float dn = dinv[n];
  const uint_t* xwu = (const uint_t*)xw;
  float ax = 0.f, ay = 0.f;
  for (int i = s0; i < s1; ++i) {
    int s = ssrc[i];
    float w = dinv[s] * dn;
    uint_t u = xwu[(size_t)s * 256 + t];
    ax += w * bf2f(u & 0xffffu);
    ay += w * bf2f(u >> 16);
  }
  float sn = selfn[n];
  uint_t su = xwu[(size_t)n * 256 + t];
  float2 b = ((const float2*)gb)[t];
  ax += sn * bf2f(su & 0xffffu) + b.x;
  ay += sn * bf2f(su >> 16) + b.y;
  float2 hv = H2<HT>::ld(h, (size_t)n * 256 + t);
  hv.x += fmaxf(ax, 0.f);
  hv.y += fmaxf(ay, 0.f);
  H2<HT>::st(h, (size_t)n * 256 + t, hv);
}

__device__ __forceinline__ int lbound(const int* a, int n, int v) {
  int lo = 0, hi = n;
  while (lo < hi) {
    int m = (lo + hi) >> 1;
    if (a[m] < v) lo = m + 1; else hi = m;
  }
  return lo;
}

template <typename HT>
__global__ void k_pool(const HT* __restrict__ h, const int* __restrict__ batch,
                       float* __restrict__ out, int N) {
  int g = blockIdx.x;
  int t = threadIdx.x;
  int start = lbound(batch, N, g);
  int end = lbound(batch, N, g + 1);
  float ax = 0.f, ay = 0.f;
  for (int n = start; n < end; ++n) {
    float2 v = H2<HT>::ld(h, (size_t)n * 256 + t);
    ax += v.x;
    ay += v.y;
  }
  float2 o; o.x = ax; o.y = ay;
  ((float2*)out)[(size_t)g * 256 + t] = o;
}

extern "C" void kernel_launch(void* const* d_in, const int* in_sizes, int n_in,
                              void* d_out, int out_size, void* d_ws, size_t ws_size,
                              hipStream_t stream) {
  const float* x  = (const float*)d_in[0];
  const int* ei   = (const int*)d_in[1];
  const int* batch= (const int*)d_in[2];
  const float* eW = (const float*)d_in[3];
  const float* eb = (const float*)d_in[4];
  const float* gW = (const float*)d_in[5];
  const float* gb = (const float*)d_in[6];
  float* out = (float*)d_out;

  const int N = in_sizes[0] / 11;
  const int E = in_sizes[1] / 2;
  const int G = out_size / 512;
  const int L = in_sizes[5] / (512 * 512);

  const int* src = ei;
  const int* dst = ei + E;

  size_t nd = (size_t)N * 512;
  auto al = [](size_t b) { return (b + 255) & ~(size_t)255; };
  // fixed-size carves (everything except h):
  size_t fixed = al(nd * 2)                     // xw (bf16)
               + al((size_t)L * 512 * 512 * 2)  // Wt
               + al((size_t)N * 4) * 4          // deg, dinv, selfn, cur
               + al(((size_t)N + 1) * 4)        // off
               + al((size_t)E * 4)              // ssrc
               + 2 * al(1024);                  // bsum, bpre
  const bool hf32 = (fixed + al(nd * 4)) <= ws_size;

  char* p = (char*)d_ws;
  auto carve = [&](size_t bytes) {
    char* q = p;
    p += (bytes + 255) & ~(size_t)255;
    return q;
  };
  void* hbuf          = carve(hf32 ? nd * 4 : nd * 2);
  ushort_t* xw        = (ushort_t*)carve(nd * 2);
  ushort_t* Wt        = (ushort_t*)carve((size_t)L * 512 * 512 * 2);
  int* deg            = (int*)carve((size_t)N * 4);
  float* dinv         = (float*)carve((size_t)N * 4);
  float* selfn        = (float*)carve((size_t)N * 4);
  int* off            = (int*)carve(((size_t)N + 1) * 4);
  int* cur            = (int*)carve((size_t)N * 4);
  int* ssrc           = (int*)carve((size_t)E * 4);
  int* bsum           = (int*)carve(1024);
  int* bpre           = (int*)carve(1024);

  k_zero<<<(N + 255) / 256, 256, 0, stream>>>(deg, N);
  k_zero<<<(N + 255) / 256, 256, 0, stream>>>(cur, N);

  int totW = L * 512 * 512;
  k_prep_w<<<(totW + 255) / 256, 256, 0, stream>>>(gW, Wt, totW);
  k_deg<<<(E + 255) / 256, 256, 0, stream>>>(dst, deg, E);
  k_dinv<<<(N + 255) / 256, 256, 0, stream>>>(deg, dinv, selfn, N);
  int nb = (N + 1023) / 1024;
  k_scan_a<<<nb, 256, 0, stream>>>(deg, off, bsum, N);
  k_scan_b<<<1, 256, 0, stream>>>(bsum, bpre, nb, off, N, E);
  k_scan_c<<<(N + 255) / 256, 256, 0, stream>>>(off, bpre, N);
  k_fill<<<(E + 255) / 256, 256, 0, stream>>>(src, dst, off, cur, ssrc, E);

  dim3 ggrid((N + 127) / 128, 4);
  if (hf32) {
    float* h = (float*)hbuf;
    k_expand<float><<<N, 256, 0, stream>>>(x, eW, eb, h, N);
    for (int l = 0; l < L; ++l) {
      k_gemm<float><<<ggrid, 256, 0, stream>>>(h, Wt + (size_t)l * 512 * 512, xw, N);
      k_agg<float><<<N, 256, 0, stream>>>(xw, h, off, ssrc, dinv, selfn, gb + (size_t)l * 512);
    }
    k_pool<float><<<G, 256, 0, stream>>>(h, batch, out, N);
  } else {
    ushort_t* h = (ushort_t*)hbuf;
    k_expand<ushort_t><<<N, 256, 0, stream>>>(x, eW, eb, h, N);
    for (int l = 0; l < L; ++l) {
      k_gemm<ushort_t><<<ggrid, 256, 0, stream>>>(h, Wt + (size_t)l * 512 * 512, xw, N);
      k_agg<ushort_t><<<N, 256, 0, stream>>>(xw, h, off, ssrc, dinv, selfn, gb + (size_t)l * 512);
    }
    k_pool<ushort_t><<<G, 256, 0, stream>>>(h, batch, out, N);
  }
}

// Round 3
// 1133.359 us; speedup vs baseline: 1.2464x; 1.2464x over previous
//
#include <hip/hip_runtime.h>
#include <hip/hip_bf16.h>
#include <stdint.h>

typedef __attribute__((ext_vector_type(8))) short bf16x8;
typedef __attribute__((ext_vector_type(4))) float f32x4;
typedef unsigned short ushort_t;
typedef unsigned int uint_t;

__device__ __forceinline__ unsigned short f2bf(float f) {
  unsigned u = __float_as_uint(f);
  u += 0x7fffu + ((u >> 16) & 1u);
  return (unsigned short)(u >> 16);
}
__device__ __forceinline__ float bf2f(unsigned u16) {
  return __uint_as_float(u16 << 16);
}

__global__ void k_zero(int* __restrict__ p, int n) {
  int i = blockIdx.x * blockDim.x + threadIdx.x;
  if (i < n) p[i] = 0;
}

// ---- weights -> bf16, swizzled [l][nt(4)][kt(16)][kg(4)][col(128)][j(8)]
// maps to W[l][k = kt*32+kg*8+j][n = nt*128+col]
__global__ void k_prep_w(const float* __restrict__ W, ushort_t* __restrict__ Wt, int total) {
  int idx = blockIdx.x * blockDim.x + threadIdx.x;
  if (idx >= total) return;
  int j   = idx & 7;
  int col = (idx >> 3) & 127;
  int kg  = (idx >> 10) & 3;
  int kt  = (idx >> 12) & 15;
  int nt  = (idx >> 16) & 3;
  int l   = idx >> 18;
  int k = kt * 32 + kg * 8 + j;
  int n = nt * 128 + col;
  Wt[idx] = f2bf(W[((size_t)(l * 512 + k)) * 512 + n]);
}

// ---- h = log1p(x) @ expW + expb   (wave per node, grid-stride, 16B stores)
__global__ __launch_bounds__(256) void k_expand(const float* __restrict__ x,
                                                const float* __restrict__ eW,
                                                const float* __restrict__ eb,
                                                ushort_t* __restrict__ h, int N) {
  const int wid = (blockIdx.x * 256 + threadIdx.x) >> 6;
  const int nw = (gridDim.x * 256) >> 6;
  const int l = threadIdx.x & 63;

  // preload W column slice [11][8] and bias [8] into registers (L2-resident)
  float wf[11][8];
  float bias[8];
#pragma unroll
  for (int f = 0; f < 11; ++f) {
    float4 a = *(const float4*)&eW[f * 512 + l * 8];
    float4 b = *(const float4*)&eW[f * 512 + l * 8 + 4];
    wf[f][0] = a.x; wf[f][1] = a.y; wf[f][2] = a.z; wf[f][3] = a.w;
    wf[f][4] = b.x; wf[f][5] = b.y; wf[f][6] = b.z; wf[f][7] = b.w;
  }
  {
    float4 a = *(const float4*)&eb[l * 8];
    float4 b = *(const float4*)&eb[l * 8 + 4];
    bias[0] = a.x; bias[1] = a.y; bias[2] = a.z; bias[3] = a.w;
    bias[4] = b.x; bias[5] = b.y; bias[6] = b.z; bias[7] = b.w;
  }

  for (int n = wid; n < N; n += nw) {
    float xv = (l < 11) ? x[(size_t)n * 11 + l] : 0.f;
    float lx = log1pf(xv);
    float acc[8];
#pragma unroll
    for (int j = 0; j < 8; ++j) acc[j] = bias[j];
#pragma unroll
    for (int f = 0; f < 11; ++f) {
      float c = __shfl(lx, f, 64);
#pragma unroll
      for (int j = 0; j < 8; ++j) acc[j] += c * wf[f][j];
    }
    uint4 pu;
    pu.x = (uint_t)f2bf(acc[0]) | ((uint_t)f2bf(acc[1]) << 16);
    pu.y = (uint_t)f2bf(acc[2]) | ((uint_t)f2bf(acc[3]) << 16);
    pu.z = (uint_t)f2bf(acc[4]) | ((uint_t)f2bf(acc[5]) << 16);
    pu.w = (uint_t)f2bf(acc[6]) | ((uint_t)f2bf(acc[7]) << 16);
    *(uint4*)(h + (size_t)n * 512 + l * 8) = pu;
  }
}

__global__ void k_deg(const int* __restrict__ dst, int* __restrict__ deg, int E) {
  int e = blockIdx.x * blockDim.x + threadIdx.x;
  if (e < E) atomicAdd(&deg[dst[e]], 1);
}

__global__ void k_dinv(const int* __restrict__ deg, float* __restrict__ dinv,
                       float* __restrict__ selfn, int N) {
  int n = blockIdx.x * blockDim.x + threadIdx.x;
  if (n >= N) return;
  float d = (float)deg[n] + 2.0f;
  dinv[n] = rsqrtf(d);
  selfn[n] = 2.0f / d;
}

// ---- 2-level exclusive scan of deg -> off (CSR offsets)
__global__ void k_scan_a(const int* __restrict__ deg, int* __restrict__ off,
                         int* __restrict__ bsum, int N) {
  __shared__ int sd[256];
  int t = threadIdx.x;
  int i0 = blockIdx.x * 1024 + t * 4;
  int d[4];
#pragma unroll
  for (int j = 0; j < 4; ++j) d[j] = (i0 + j < N) ? deg[i0 + j] : 0;
  int ts = d[0] + d[1] + d[2] + d[3];
  sd[t] = ts;
  __syncthreads();
  for (int o = 1; o < 256; o <<= 1) {
    int v = (t >= o) ? sd[t - o] : 0;
    __syncthreads();
    sd[t] += v;
    __syncthreads();
  }
  int incl = sd[t];
  int run = incl - ts;
#pragma unroll
  for (int j = 0; j < 4; ++j) {
    if (i0 + j < N) off[i0 + j] = run;
    run += d[j];
  }
  if (t == 255) bsum[blockIdx.x] = incl;
}

__global__ void k_scan_b(const int* __restrict__ bsum, int* __restrict__ bpre, int nb,
                         int* __restrict__ off, int N, int E) {
  __shared__ int sd[256];
  int t = threadIdx.x;
  int v = (t < nb) ? bsum[t] : 0;
  sd[t] = v;
  __syncthreads();
  for (int o = 1; o < 256; o <<= 1) {
    int u = (t >= o) ? sd[t - o] : 0;
    __syncthreads();
    sd[t] += u;
    __syncthreads();
  }
  if (t < nb) bpre[t] = sd[t] - v;
  if (t == 0) off[N] = E;
}

__global__ void k_scan_c(int* __restrict__ off, const int* __restrict__ bpre, int N) {
  int i = blockIdx.x * blockDim.x + threadIdx.x;
  if (i < N) off[i] += bpre[i >> 10];
}

__global__ void k_fill(const int* __restrict__ src, const int* __restrict__ dst,
                       const int* __restrict__ off, int* __restrict__ cur,
                       int* __restrict__ ssrc, int E) {
  int e = blockIdx.x * blockDim.x + threadIdx.x;
  if (e >= E) return;
  int t = dst[e];
  int p = atomicAdd(&cur[t], 1);
  ssrc[off[t] + p] = src[e];
}

// ---- xw = h @ W[l]  (bf16 MFMA, 128x128 tile, 4 waves of 64x64, BK=32)
__global__ __launch_bounds__(256) void k_gemm(const ushort_t* __restrict__ h,
                                              const ushort_t* __restrict__ Wt,
                                              ushort_t* __restrict__ xw, int N) {
  __shared__ alignas(16) short Alds[4 * 128 * 8];  // [kg][row][8]
  __shared__ alignas(16) short Blds[4 * 128 * 8];  // [kg][col][8]
  const int tid = threadIdx.x;
  const int m0 = blockIdx.x * 128;
  const int nt = blockIdx.y;
  const int wv = tid >> 6, ln = tid & 63;
  const int wrow = wv >> 1, wcol = wv & 1;
  const int l15 = ln & 15, l4 = ln >> 4;

  f32x4 acc[4][4];
#pragma unroll
  for (int i = 0; i < 4; ++i)
#pragma unroll
    for (int j = 0; j < 4; ++j) acc[i][j] = (f32x4){0.f, 0.f, 0.f, 0.f};

  const int r = tid >> 1, hh = tid & 1;
  const int grow = m0 + r;
  const bool valid = grow < N;
  const ushort_t* hrow = h + (size_t)grow * 512 + hh * 16;
  const int abase0 = ((hh * 2 + 0) * 128 + r) * 8;
  const int abase1 = ((hh * 2 + 1) * 128 + r) * 8;

  for (int kt = 0; kt < 16; ++kt) {
    __syncthreads();
    // B stage: 8KB linear global_load_lds (Wt pre-swizzled to LDS layout)
    {
      const ushort_t* wt = Wt + (((size_t)nt * 16 + kt) << 12);
      const ushort_t* g1 = wt + ((wv * 64 + ln) << 3);
      const ushort_t* g2 = g1 + 2048;
      __builtin_amdgcn_global_load_lds(
          (const __attribute__((address_space(1))) unsigned int*)g1,
          (__attribute__((address_space(3))) unsigned int*)&Blds[(wv * 64) << 3], 16, 0, 0);
      __builtin_amdgcn_global_load_lds(
          (const __attribute__((address_space(1))) unsigned int*)g2,
          (__attribute__((address_space(3))) unsigned int*)&Blds[(256 + wv * 64) << 3], 16, 0, 0);
    }
    // A stage: 16 bf16 k-values, ds_write
    {
      bf16x8 v0, v1;
      if (valid) {
        v0 = ((const bf16x8*)(hrow + kt * 32))[0];
        v1 = ((const bf16x8*)(hrow + kt * 32))[1];
      } else {
        v0 = (bf16x8){0, 0, 0, 0, 0, 0, 0, 0};
        v1 = v0;
      }
      *(bf16x8*)&Alds[abase0] = v0;
      *(bf16x8*)&Alds[abase1] = v1;
    }
    __syncthreads();
    bf16x8 a[4], b[4];
#pragma unroll
    for (int i = 0; i < 4; ++i) {
      a[i] = *(const bf16x8*)&Alds[(l4 * 128 + wrow * 64 + i * 16 + l15) * 8];
      b[i] = *(const bf16x8*)&Blds[(l4 * 128 + wcol * 64 + i * 16 + l15) * 8];
    }
#pragma unroll
    for (int i = 0; i < 4; ++i)
#pragma unroll
      for (int j = 0; j < 4; ++j)
        acc[i][j] = __builtin_amdgcn_mfma_f32_16x16x32_bf16(a[i], b[j], acc[i][j], 0, 0, 0);
  }

#pragma unroll
  for (int i = 0; i < 4; ++i) {
    int row0 = m0 + wrow * 64 + i * 16 + l4 * 4;
#pragma unroll
    for (int v = 0; v < 4; ++v) {
      int row = row0 + v;
      if (row < N) {
#pragma unroll
        for (int j = 0; j < 4; ++j) {
          int col = nt * 128 + wcol * 64 + j * 16 + l15;
          xw[(size_t)row * 512 + col] = f2bf(acc[i][j][v]);
        }
      }
    }
  }
}

// ---- fused: agg = sum_in enorm*xw[src] + self*xw[n] + b ; h += relu(agg)
// wave per node, grid-stride, 16B gathers
__global__ __launch_bounds__(256) void k_agg(const ushort_t* __restrict__ xw,
                                             ushort_t* __restrict__ h,
                                             const int* __restrict__ off,
                                             const int* __restrict__ ssrc,
                                             const float* __restrict__ dinv,
                                             const float* __restrict__ selfn,
                                             const float* __restrict__ gb, int N) {
  const int wid = (blockIdx.x * 256 + threadIdx.x) >> 6;
  const int nw = (gridDim.x * 256) >> 6;
  const int l = threadIdx.x & 63;

  float bias[8];
  {
    float4 a = *(const float4*)&gb[l * 8];
    float4 b = *(const float4*)&gb[l * 8 + 4];
    bias[0] = a.x; bias[1] = a.y; bias[2] = a.z; bias[3] = a.w;
    bias[4] = b.x; bias[5] = b.y; bias[6] = b.z; bias[7] = b.w;
  }

  for (int n = wid; n < N; n += nw) {
    int s0 = off[n], s1 = off[n + 1];
    float dn = dinv[n];
    float acc[8];
#pragma unroll
    for (int j = 0; j < 8; ++j) acc[j] = bias[j];
    for (int i = s0; i < s1; ++i) {
      int s = ssrc[i];
      float w = dn * dinv[s];
      uint4 u = *(const uint4*)(xw + (size_t)s * 512 + l * 8);
      acc[0] += w * bf2f(u.x & 0xffffu); acc[1] += w * bf2f(u.x >> 16);
      acc[2] += w * bf2f(u.y & 0xffffu); acc[3] += w * bf2f(u.y >> 16);
      acc[4] += w * bf2f(u.z & 0xffffu); acc[5] += w * bf2f(u.z >> 16);
      acc[6] += w * bf2f(u.w & 0xffffu); acc[7] += w * bf2f(u.w >> 16);
    }
    float sn = selfn[n];
    {
      uint4 u = *(const uint4*)(xw + (size_t)n * 512 + l * 8);
      acc[0] += sn * bf2f(u.x & 0xffffu); acc[1] += sn * bf2f(u.x >> 16);
      acc[2] += sn * bf2f(u.y & 0xffffu); acc[3] += sn * bf2f(u.y >> 16);
      acc[4] += sn * bf2f(u.z & 0xffffu); acc[5] += sn * bf2f(u.z >> 16);
      acc[6] += sn * bf2f(u.w & 0xffffu); acc[7] += sn * bf2f(u.w >> 16);
    }
    uint4 hu = *(const uint4*)(h + (size_t)n * 512 + l * 8);
    float hv[8];
    hv[0] = bf2f(hu.x & 0xffffu); hv[1] = bf2f(hu.x >> 16);
    hv[2] = bf2f(hu.y & 0xffffu); hv[3] = bf2f(hu.y >> 16);
    hv[4] = bf2f(hu.z & 0xffffu); hv[5] = bf2f(hu.z >> 16);
    hv[6] = bf2f(hu.w & 0xffffu); hv[7] = bf2f(hu.w >> 16);
#pragma unroll
    for (int j = 0; j < 8; ++j) hv[j] += fmaxf(acc[j], 0.f);
    uint4 pu;
    pu.x = (uint_t)f2bf(hv[0]) | ((uint_t)f2bf(hv[1]) << 16);
    pu.y = (uint_t)f2bf(hv[2]) | ((uint_t)f2bf(hv[3]) << 16);
    pu.z = (uint_t)f2bf(hv[4]) | ((uint_t)f2bf(hv[5]) << 16);
    pu.w = (uint_t)f2bf(hv[6]) | ((uint_t)f2bf(hv[7]) << 16);
    *(uint4*)(h + (size_t)n * 512 + l * 8) = pu;
  }
}

__device__ __forceinline__ int lbound(const int* a, int n, int v) {
  int lo = 0, hi = n;
  while (lo < hi) {
    int m = (lo + hi) >> 1;
    if (a[m] < v) lo = m + 1; else hi = m;
  }
  return lo;
}

// ---- global_add_pool: block per graph, 16B loads, 4-way row parallel + LDS reduce
__global__ __launch_bounds__(256) void k_pool(const ushort_t* __restrict__ h,
                                              const int* __restrict__ batch,
                                              float* __restrict__ out, int N) {
  __shared__ float red[4 * 512];
  int g = blockIdx.x;
  int t = threadIdx.x;
  int w = t >> 6, l = t & 63;
  int start = lbound(batch, N, g);
  int end = lbound(batch, N, g + 1);
  float acc[8];
#pragma unroll
  for (int j = 0; j < 8; ++j) acc[j] = 0.f;
  for (int n = start + w; n < end; n += 4) {
    uint4 u = *(const uint4*)(h + (size_t)n * 512 + l * 8);
    acc[0] += bf2f(u.x & 0xffffu); acc[1] += bf2f(u.x >> 16);
    acc[2] += bf2f(u.y & 0xffffu); acc[3] += bf2f(u.y >> 16);
    acc[4] += bf2f(u.z & 0xffffu); acc[5] += bf2f(u.z >> 16);
    acc[6] += bf2f(u.w & 0xffffu); acc[7] += bf2f(u.w >> 16);
  }
#pragma unroll
  for (int j = 0; j < 8; ++j) red[w * 512 + l * 8 + j] = acc[j];
  __syncthreads();
  if (t < 128) {
    float4 s = make_float4(0.f, 0.f, 0.f, 0.f);
#pragma unroll
    for (int ww = 0; ww < 4; ++ww) {
      float4 v = *(const float4*)&red[ww * 512 + t * 4];
      s.x += v.x; s.y += v.y; s.z += v.z; s.w += v.w;
    }
    *(float4*)&out[(size_t)g * 512 + t * 4] = s;
  }
}

extern "C" void kernel_launch(void* const* d_in, const int* in_sizes, int n_in,
                              void* d_out, int out_size, void* d_ws, size_t ws_size,
                              hipStream_t stream) {
  const float* x  = (const float*)d_in[0];
  const int* ei   = (const int*)d_in[1];
  const int* batch= (const int*)d_in[2];
  const float* eW = (const float*)d_in[3];
  const float* eb = (const float*)d_in[4];
  const float* gW = (const float*)d_in[5];
  const float* gb = (const float*)d_in[6];
  float* out = (float*)d_out;

  const int N = in_sizes[0] / 11;
  const int E = in_sizes[1] / 2;
  const int G = out_size / 512;
  const int L = in_sizes[5] / (512 * 512);

  const int* src = ei;
  const int* dst = ei + E;

  size_t nd = (size_t)N * 512;
  char* p = (char*)d_ws;
  auto carve = [&](size_t bytes) {
    char* q = p;
    p += (bytes + 255) & ~(size_t)255;
    return q;
  };
  ushort_t* h         = (ushort_t*)carve(nd * 2);
  ushort_t* xw        = (ushort_t*)carve(nd * 2);
  ushort_t* Wt        = (ushort_t*)carve((size_t)L * 512 * 512 * 2);
  int* deg            = (int*)carve((size_t)N * 4);
  float* dinv         = (float*)carve((size_t)N * 4);
  float* selfn        = (float*)carve((size_t)N * 4);
  int* off            = (int*)carve(((size_t)N + 1) * 4);
  int* cur            = (int*)carve((size_t)N * 4);
  int* ssrc           = (int*)carve((size_t)E * 4);
  int* bsum           = (int*)carve(1024);
  int* bpre           = (int*)carve(1024);

  k_zero<<<(N + 255) / 256, 256, 0, stream>>>(deg, N);
  k_zero<<<(N + 255) / 256, 256, 0, stream>>>(cur, N);

  int totW = L * 512 * 512;
  k_prep_w<<<(totW + 255) / 256, 256, 0, stream>>>(gW, Wt, totW);
  k_expand<<<2048, 256, 0, stream>>>(x, eW, eb, h, N);
  k_deg<<<(E + 255) / 256, 256, 0, stream>>>(dst, deg, E);
  k_dinv<<<(N + 255) / 256, 256, 0, stream>>>(deg, dinv, selfn, N);
  int nb = (N + 1023) / 1024;
  k_scan_a<<<nb, 256, 0, stream>>>(deg, off, bsum, N);
  k_scan_b<<<1, 256, 0, stream>>>(bsum, bpre, nb, off, N, E);
  k_scan_c<<<(N + 255) / 256, 256, 0, stream>>>(off, bpre, N);
  k_fill<<<(E + 255) / 256, 256, 0, stream>>>(src, dst, off, cur, ssrc, E);

  dim3 ggrid((N + 127) / 128, 4);
  for (int l = 0; l < L; ++l) {
    k_gemm<<<ggrid, 256, 0, stream>>>(h, Wt + (size_t)l * 512 * 512, xw, N);
    k_agg<<<2048, 256, 0, stream>>>(xw, h, off, ssrc, dinv, selfn, gb + (size_t)l * 512, N);
  }
  k_pool<<<G, 256, 0, stream>>>(h, batch, out, N);
}